// Round 10
// baseline (931.956 us; speedup 1.0000x reference)
//
#include <hip/hip_runtime.h>
#include <stdint.h>

// ---------------- workspace layout (float elements) ----------------
//  [0..3]  w absmax bits   [4..7] w_sf   [8..11] b_sf
//  [16..33] head absmax bits (q/k/v * 6 heads)
//  [128..143] grid-barrier slots (cnt,gen pairs)
#define WS_WT     1024                        // w16 frag-order: 4 mats * 147456 ushort
#define WS_BI     (1024 + 4*147456)           // 590848 (float b_int)
#define WS_QBUF   (WS_BI + 1536)              // 592384: qkv fp32 (3*NE); later attn planes
#define NROW      8192
#define NE        (NROW*384)                  // 3145728
#define WS_C8     (WS_QBUF + 3*NE)            // xplanes (2*NE ushort) then q8/k8/vf
#define NBLK      576

typedef __attribute__((ext_vector_type(4))) int      i32x4;
typedef __attribute__((ext_vector_type(4))) float    f32x4;
typedef __attribute__((ext_vector_type(8))) _Float16 f16x8;

__device__ __forceinline__ void gl2lds16(const void* g, void* lds_uniform) {
    __builtin_amdgcn_global_load_lds(
        (const __attribute__((address_space(1))) unsigned*)g,
        (__attribute__((address_space(3))) unsigned*)lds_uniform, 16, 0, 0);
}

__global__ __launch_bounds__(256) void k_init(float* ws) {
    ws[threadIdx.x] = 0.0f;   // zero scalar/atomic/barrier slots
}

// device-scope grid barrier; each phase uses a distinct slot idx
__device__ __forceinline__ void gbar(unsigned* bar, int idx) {
    __syncthreads();
    if (threadIdx.x == 0) {
        __threadfence();
        unsigned* cnt = bar + 2 * idx;
        unsigned* gen = bar + 2 * idx + 1;
        unsigned g = __hip_atomic_load(gen, __ATOMIC_ACQUIRE, __HIP_MEMORY_SCOPE_AGENT);
        unsigned a = __hip_atomic_fetch_add(cnt, 1u, __ATOMIC_ACQ_REL, __HIP_MEMORY_SCOPE_AGENT);
        if (a == gridDim.x - 1) {
            __hip_atomic_fetch_add(gen, 1u, __ATOMIC_ACQ_REL, __HIP_MEMORY_SCOPE_AGENT);
        } else {
            while (__hip_atomic_load(gen, __ATOMIC_ACQUIRE, __HIP_MEMORY_SCOPE_AGENT) == g)
                __builtin_amdgcn_s_sleep(4);
        }
        __threadfence();
    }
    __syncthreads();
}

__device__ __forceinline__ float blockmax_and_get(float lmax, float* red) {
    #pragma unroll
    for (int off = 32; off; off >>= 1) lmax = fmaxf(lmax, __shfl_xor(lmax, off, 64));
    int wv = threadIdx.x >> 6, ln = threadIdx.x & 63;
    if (ln == 0) red[wv] = lmax;
    __syncthreads();
    return fmaxf(fmaxf(red[0], red[1]), fmaxf(red[2], red[3]));
}

__device__ __forceinline__ unsigned short f16bits(float x) {
    _Float16 h = (_Float16)x;
    unsigned short u;
    __builtin_memcpy(&u, &h, 2);
    return u;
}

// round-8-proven LDS-DMA double-buffered GEMM, as a device phase.
// Block tile (RTB*16) x 128; 4 waves; smemb = 2*NF fragments of 1 KB.
template<int RTB, bool QKV>
__device__ void gemm_phase(unsigned short* smemb, int mtile, int nt,
                           const unsigned short* xhi, const unsigned short* xlo,
                           float* ws, float* out) {
    constexpr int NF = 2 * RTB + 8;
    constexpr int RT = RTB / 2;
    const unsigned short* w16 = (const unsigned short*)(ws + WS_WT) + (QKV ? (nt / 3) : 3) * 147456;
    int mat = QKV ? (nt / 3) : 3;
    int cb  = QKV ? ((nt % 3) * 128) : (nt * 128);
    const float* bi = ws + WS_BI + mat * 384;
    float bsf = ws[8 + mat];

    int tid = threadIdx.x, w = tid >> 6, lane = tid & 63;
    int rtg0 = mtile * RTB;
    int ctg0 = cb >> 4;
    int rl0 = (w & 1) * RT, cl0 = (w >> 1) * 4;

    auto stage = [&](int buf, int k) {
        #pragma unroll
        for (int i = 0; i < NF / 4; i++) {
            int f = w * (NF / 4) + i;
            const unsigned short* g;
            if (f < RTB)           g = xhi + ((rtg0 + f) * 12 + k) * 512;
            else if (f < 2 * RTB)  g = xlo + ((rtg0 + f - RTB) * 12 + k) * 512;
            else                   g = w16 + ((ctg0 + f - 2 * RTB) * 12 + k) * 512;
            gl2lds16(g + lane * 8, &smemb[(buf * NF + f) * 512]);
        }
    };

    f32x4 acc[RT][4] = {};
    stage(0, 0);
    __syncthreads();
    for (int k = 0; k < 12; k++) {
        if (k < 11) stage((k + 1) & 1, k + 1);
        const unsigned short* sb = smemb + (k & 1) * NF * 512;
        f16x8 bf[4];
        #pragma unroll
        for (int ct = 0; ct < 4; ct++)
            bf[ct] = *(const f16x8*)&sb[(2 * RTB + cl0 + ct) * 512 + lane * 8];
        #pragma unroll
        for (int rt = 0; rt < RT; rt++) {
            f16x8 hi = *(const f16x8*)&sb[(rl0 + rt) * 512 + lane * 8];
            f16x8 lo = *(const f16x8*)&sb[(RTB + rl0 + rt) * 512 + lane * 8];
            #pragma unroll
            for (int ct = 0; ct < 4; ct++) {
                acc[rt][ct] = __builtin_amdgcn_mfma_f32_16x16x32_f16(lo, bf[ct], acc[rt][ct], 0, 0, 0);
                acc[rt][ct] = __builtin_amdgcn_mfma_f32_16x16x32_f16(hi, bf[ct], acc[rt][ct], 0, 0, 0);
            }
        }
        __syncthreads();
    }

    int quad = lane >> 4, l15 = lane & 15;
    float lmax = 0.f;
    #pragma unroll
    for (int rt = 0; rt < RT; rt++) {
        #pragma unroll
        for (int r = 0; r < 4; r++) {
            int row = (rtg0 + rl0 + rt) * 16 + quad * 4 + r;
            #pragma unroll
            for (int ct = 0; ct < 4; ct++) {
                int col = (ctg0 + cl0 + ct) * 16 + l15;
                float v = __fmul_rn(__fadd_rn(acc[rt][ct][r], bi[col]), bsf);
                lmax = fmaxf(lmax, fabsf(v));
                out[row * 384 + col] = v;
            }
        }
    }
    if (QKV) {
        #pragma unroll
        for (int off = 32; off; off >>= 1) lmax = fmaxf(lmax, __shfl_xor(lmax, off, 64));
        int hd = (cb >> 6) + (w >> 1);
        if (lane == 0)
            atomicMax((unsigned int*)&ws[16 + mat * 6 + hd], __float_as_uint(lmax));
    } else {
        if (mtile == 0 && nt == 0 && tid == 0) out[NE] = bsf;   // out_sf
    }
}

struct HeadScales {
    float qsf, ksf, vsf, sf, x0i, bpoly, cint, expsf, s16, thirty;
};
__device__ __forceinline__ HeadScales head_scales(const float* ws, int h) {
    const unsigned* wu = (const unsigned*)ws;
    HeadScales r;
    r.qsf = fmaxf(__uint_as_float(wu[16 + h]), 1e-8f) / 127.0f;
    r.ksf = fmaxf(__uint_as_float(wu[22 + h]), 1e-8f) / 127.0f;
    r.vsf = fmaxf(__uint_as_float(wu[28 + h]), 1e-8f) / 127.0f;
    r.sf = __fmul_rn(r.ksf, r.qsf);
    const float X0f = -0.6931f;
    const float C0f = 0.35815147f;
    const float C1f = (float)(0.96963238 / 0.35815147);
    const float C2f = (float)(1.0 / 0.35815147);
    r.x0i   = floorf(X0f / r.sf);
    r.bpoly = floorf(C1f / r.sf);
    float sfsq = __fmul_rn(r.sf, r.sf);
    r.cint  = floorf(C2f / sfsq);
    float psf = __fmul_rn(C0f, sfsq);
    r.expsf = psf / 1073741824.0f;
    float rawmax = __fmul_rn(r.cint, 1073741824.0f);
    r.s16 = fmaxf(__fmul_rn(rawmax, r.expsf), 1e-8f) / 32767.0f;
    r.thirty = __fmul_rn(30.0f, r.x0i);
    return r;
}

__global__ __launch_bounds__(256, 3) void k_mega(
        const float* __restrict__ x, const float* __restrict__ xsf,
        const float* __restrict__ w0, const float* __restrict__ b0,
        const float* __restrict__ w1, const float* __restrict__ b1,
        const float* __restrict__ w2, const float* __restrict__ b2,
        const float* __restrict__ w3, const float* __restrict__ b3,
        float* ws, float* out) {
    __shared__ unsigned short smem[2 * 24 * 512];   // 48 KB: GEMM dbuf / attn pS overlay
    unsigned* bar = (unsigned*)(ws + 128);
    const unsigned* wu = (const unsigned*)ws;
    int bid = blockIdx.x, tid = threadIdx.x;

    float* qkv = ws + WS_QBUF;
    unsigned short* xhi = (unsigned short*)(ws + WS_C8);
    unsigned short* xlo = xhi + NE;
    char* q8 = (char*)(ws + WS_C8);
    char* k8 = q8 + NE;
    unsigned short* vf = (unsigned short*)(k8 + NE);
    unsigned short* abhi = (unsigned short*)(ws + WS_QBUF + NE);
    unsigned short* ablo = abhi + NE;

    // ---- phase A: weight absmax (144 units) + x split to f16 planes (3072 units)
    if (bid < 144) {
        int m = bid / 36, chunk = bid % 36;
        const float* w = (m == 0) ? w0 : (m == 1) ? w1 : (m == 2) ? w2 : w3;
        int base = chunk * 4096 + tid;
        float lmax = 0.f;
        #pragma unroll
        for (int i = 0; i < 16; i++) lmax = fmaxf(lmax, fabsf(w[base + i * 256]));
        __shared__ float red[4];
        float m4 = blockmax_and_get(lmax, red);
        if (tid == 0) atomicMax((unsigned int*)&ws[m], __float_as_uint(m4));
    }
    {
        float xs = xsf[0];
        for (int u = bid; u < 3072; u += NBLK) {
            int gid = u * 256 + tid;
            int e0 = gid * 4;
            int row = e0 / 384, k = e0 - row * 384;
            float4 v = *(const float4*)&x[e0];
            float f[4] = {v.x, v.y, v.z, v.w};
            unsigned short hb[4], lb[4];
            #pragma unroll
            for (int i = 0; i < 4; i++) {
                float xi = f[i] / xs;
                _Float16 h = (_Float16)xi;
                float hf = (float)h;
                _Float16 l = (_Float16)__fsub_rn(xi, hf);
                __builtin_memcpy(&hb[i], &h, 2);
                __builtin_memcpy(&lb[i], &l, 2);
            }
            int base = ((row >> 4) * 12 + (k >> 5)) * 512 + ((((k & 31) >> 3) << 4) + (row & 15)) * 8 + (k & 7);
            uint2 hp = make_uint2((unsigned)hb[0] | ((unsigned)hb[1] << 16),
                                  (unsigned)hb[2] | ((unsigned)hb[3] << 16));
            uint2 lp = make_uint2((unsigned)lb[0] | ((unsigned)lb[1] << 16),
                                  (unsigned)lb[2] | ((unsigned)lb[3] << 16));
            *(uint2*)(xhi + base) = hp;
            *(uint2*)(xlo + base) = lp;
        }
    }
    gbar(bar, 0);

    // ---- phase B: weight/bias quantization (577 units)
    for (int u = bid; u < 577; u += NBLK) {
        if (u < 576) {
            int m = u / 144, chunk = u % 144;
            const float* w = (m == 0) ? w0 : (m == 1) ? w1 : (m == 2) ? w2 : w3;
            float s = fmaxf(__uint_as_float(wu[m]), 1e-8f) / 127.0f;
            unsigned short* wt16 = (unsigned short*)(ws + WS_WT) + m * 147456;
            int base = chunk * 1024 + tid;
            #pragma unroll
            for (int i = 0; i < 4; i++) {
                int e = base + i * 256;
                int o = e / 384, k = e - o * 384;
                float q = fminf(fmaxf(rintf(w[e] / s), -128.f), 127.f);
                _Float16 qh = (_Float16)q;
                unsigned short qb;
                __builtin_memcpy(&qb, &qh, 2);
                int idx = ((o >> 4) * 12 + (k >> 5)) * 512 + ((((k & 31) >> 3) << 4) + (o & 15)) * 8 + (k & 7);
                wt16[idx] = qb;
            }
        } else {
            for (int idx = tid; idx < 1536; idx += 256) {
                int m = idx / 384, o = idx - m * 384;
                const float* b = (m == 0) ? b0 : (m == 1) ? b1 : (m == 2) ? b2 : b3;
                float s = fmaxf(__uint_as_float(wu[m]), 1e-8f) / 127.0f;
                float bsf = (m < 3) ? __fmul_rn(s, xsf[0]) : __fmul_rn(s, 0.00390625f);
                float bq = fminf(fmaxf(rintf(b[o] / bsf), -2147483648.0f), 2147483648.0f);
                ws[WS_BI + m * 384 + o] = bq;
                if (o == 0) { ws[4 + m] = s; ws[8 + m] = bsf; }
            }
        }
    }
    gbar(bar, 1);

    // ---- phase C: QKV GEMM (576 blocks, 1:1)
    gemm_phase<8, true>(smem, bid & 63, bid >> 6, xhi, xlo, ws,
                        qkv + (bid >> 6) / 3 * NE);
    gbar(bar, 2);

    // ---- phase D: prequant q8/k8/vf (9216 units)
    for (int u = bid; u < 9216; u += NBLK) {
        int sec = u / 3072;
        int id = (u % 3072) * 256 + tid;
        if (sec < 2) {
            const float* src = sec ? (qkv + NE) : qkv;
            int row = id / 96, c4 = (id % 96) * 4;
            int h = c4 >> 6;
            float s = fmaxf(__uint_as_float(wu[16 + (sec ? 6 : 0) + h]), 1e-8f) / 127.0f;
            float4 v = *(const float4*)&src[row * 384 + c4];
            int a0 = (int)fminf(fmaxf(rintf(v.x / s), -128.f), 127.f);
            int a1 = (int)fminf(fmaxf(rintf(v.y / s), -128.f), 127.f);
            int a2 = (int)fminf(fmaxf(rintf(v.z / s), -128.f), 127.f);
            int a3 = (int)fminf(fmaxf(rintf(v.w / s), -128.f), 127.f);
            unsigned pk = (unsigned)(a0 & 255) | ((unsigned)(a1 & 255) << 8) |
                          ((unsigned)(a2 & 255) << 16) | ((unsigned)(a3 & 255) << 24);
            ((unsigned*)(sec ? k8 : q8))[id] = pk;
        } else {
            const float* vb = qkv + 2 * NE;
            int d = id & 63;
            int rest = id >> 6;
            int kvg = rest & 63;
            int bh = rest >> 6;
            int b = bh / 6, h = bh - (bh / 6) * 6;
            float s = fmaxf(__uint_as_float(wu[28 + h]), 1e-8f) / 127.0f;
            int kv0 = kvg * 4;
            float v0 = vb[(b * 256 + kv0 + 0) * 384 + h * 64 + d];
            float v1 = vb[(b * 256 + kv0 + 1) * 384 + h * 64 + d];
            float v2 = vb[(b * 256 + kv0 + 2) * 384 + h * 64 + d];
            float v3 = vb[(b * 256 + kv0 + 3) * 384 + h * 64 + d];
            unsigned short u0 = f16bits(fminf(fmaxf(rintf(v0 / s), -128.f), 127.f));
            unsigned short u1 = f16bits(fminf(fmaxf(rintf(v1 / s), -128.f), 127.f));
            unsigned short u2 = f16bits(fminf(fmaxf(rintf(v2 / s), -128.f), 127.f));
            unsigned short u3 = f16bits(fminf(fmaxf(rintf(v3 / s), -128.f), 127.f));
            unsigned pk01 = (unsigned)u0 | ((unsigned)u1 << 16);
            unsigned pk23 = (unsigned)u2 | ((unsigned)u3 << 16);
            int c = kv0 >> 5, quad = (kv0 >> 3) & 3, j0 = kv0 & 7;
            int base = ((bh * 8 + c) * 4 + (d >> 4)) * 512 + (quad * 16 + (d & 15)) * 8 + j0;
            *(uint2*)&vf[base] = make_uint2(pk01, pk23);
        }
    }
    gbar(bar, 3);

    // ---- phase E: fused attention (768 units)
    for (int u = bid; u < 768; u += NBLK) {
        _Float16* pS = (_Float16*)smem;   // [4][64][8] wave-private overlay
        int qt = u & 3, bh = u >> 2;
        int b = bh / 6, h = bh - (bh / 6) * 6;
        HeadScales S = head_scales(ws, h);
        int w = tid >> 6, lane = tid & 63;
        int quad = lane >> 4, l15 = lane & 15;
        int strip0 = qt * 64 + w * 16;
        int ntiles = (strip0 >> 4) + 1;

        const i32x4 afrag = *(const i32x4*)(q8 + (b * 256 + strip0 + l15) * 384 + h * 64 + quad * 16);

        f32x4 xi[16];
        i32x4 zero4 = {0, 0, 0, 0};
        #pragma unroll
        for (int ct = 0; ct < 16; ct++) {
            if (ct < ntiles) {
                i32x4 bfrag = *(const i32x4*)(k8 + (b * 256 + ct * 16 + l15) * 384 + h * 64 + quad * 16);
                i32x4 c = __builtin_amdgcn_mfma_i32_16x16x64_i8(afrag, bfrag, zero4, 0, 0, 0);
                #pragma unroll
                for (int r = 0; r < 4; r++) {
                    float wei = __fmul_rn(__fmul_rn(__fmul_rn((float)c[r], S.qsf), S.ksf), 0.125f);
                    xi[ct][r] = wei / S.sf;
                }
            }
        }

        float NI = -__builtin_inff();
        f32x4 m = {NI, NI, NI, NI};
        #pragma unroll
        for (int ct = 0; ct < 16; ct++) {
            if (ct < ntiles) {
                bool last = (ct == ntiles - 1);
                #pragma unroll
                for (int r = 0; r < 4; r++)
                    if (!last || (l15 <= quad * 4 + r)) m[r] = fmaxf(m[r], xi[ct][r]);
            }
        }
        #pragma unroll
        for (int o = 8; o; o >>= 1) {
            m.x = fmaxf(m.x, __shfl_xor(m.x, o));
            m.y = fmaxf(m.y, __shfl_xor(m.y, o));
            m.z = fmaxf(m.z, __shfl_xor(m.z, o));
            m.w = fmaxf(m.w, __shfl_xor(m.w, o));
        }

        f32x4 sum = {0.f, 0.f, 0.f, 0.f};
        #pragma unroll
        for (int ct = 0; ct < 16; ct++) {
            if (ct < ntiles) {
                bool last = (ct == ntiles - 1);
                #pragma unroll
                for (int r = 0; r < 4; r++) {
                    float ei = 0.f;
                    if (!last || (l15 <= quad * 4 + r)) {
                        float xsv = fmaxf(__fsub_rn(xi[ct][r], m[r]), S.thirty);
                        float qf = floorf(xsv / S.x0i);
                        float rr = __fsub_rn(xsv, __fmul_rn(S.x0i, qf));
                        float z = __fadd_rn(__fmul_rn(__fadd_rn(rr, S.bpoly), rr), S.cint);
                        float p2 = ldexpf(1.0f, 30 - (int)qf);
                        float eraw = fmaxf(floorf(__fmul_rn(z, p2)), 0.0f);
                        float esc = __fmul_rn(eraw, S.expsf);
                        float q16 = fminf(fmaxf(rintf(esc / S.s16), -32768.f), 32767.f);
                        float e = __fmul_rn(q16, S.s16);
                        ei = e / S.s16;
                    }
                    xi[ct][r] = ei;
                    sum[r] += ei;
                }
            }
        }
        #pragma unroll
        for (int o = 8; o; o >>= 1) {
            sum.x += __shfl_xor(sum.x, o);
            sum.y += __shfl_xor(sum.y, o);
            sum.z += __shfl_xor(sum.z, o);
            sum.w += __shfl_xor(sum.w, o);
        }
        f32x4 fac;
        #pragma unroll
        for (int r = 0; r < 4; r++) fac[r] = floorf(4294967296.0f / sum[r]);

        #pragma unroll
        for (int ct = 0; ct < 16; ct++) {
            #pragma unroll
            for (int r = 0; r < 4; r++) {
                if (ct < ntiles)
                    xi[ct][r] = floorf(__fmul_rn(__fmul_rn(xi[ct][r], fac[r]), 5.9604644775390625e-08f));
                else
                    xi[ct][r] = 0.f;
            }
        }

        f32x4 o4[4] = {};
        int nch = (ntiles + 1) >> 1;
        #pragma unroll
        for (int c = 0; c < 8; c++) {
            if (c < nch) {
                #pragma unroll
                for (int t2 = 0; t2 < 2; t2++) {
                    int qd = t2 * 2 + (l15 >> 3);
                    #pragma unroll
                    for (int r = 0; r < 4; r++)
                        pS[((w * 64) + qd * 16 + quad * 4 + r) * 8 + (l15 & 7)] = (_Float16)xi[2 * c + t2][r];
                }
                f16x8 pa = *(f16x8*)&pS[(w * 64 + lane) * 8];
                int vbase = ((bh * 8 + c) * 4) * 512 + lane * 8;
                #pragma unroll
                for (int cc = 0; cc < 4; cc++) {
                    f16x8 vbf = *(const f16x8*)&vf[vbase + cc * 512];
                    o4[cc] = __builtin_amdgcn_mfma_f32_16x16x32_f16(pa, vbf, o4[cc], 0, 0, 0);
                }
            }
        }

        int rowt12 = ((b * 256 + strip0) >> 4) * 12;
        #pragma unroll
        for (int cc = 0; cc < 4; cc++) {
            int fb = (rowt12 + h * 2 + (cc >> 1)) * 512;
            int sub = ((cc & 1) * 2 + (l15 >> 3)) * 16;
            #pragma unroll
            for (int r = 0; r < 4; r++) {
                float v = __fmul_rn(__fmul_rn(o4[cc][r], S.vsf), 0.00390625f);
                _Float16 hh = (_Float16)v;
                float hf = (float)hh;
                _Float16 ll = (_Float16)__fsub_rn(v, hf);
                unsigned short hbb, lbb;
                __builtin_memcpy(&hbb, &hh, 2);
                __builtin_memcpy(&lbb, &ll, 2);
                int idx = fb + (sub + quad * 4 + r) * 8 + (l15 & 7);
                abhi[idx] = hbb;
                ablo[idx] = lbb;
            }
        }
    }
    gbar(bar, 4);

    // ---- phase F: output projection GEMM (384 blocks)
    if (bid < 384)
        gemm_phase<4, false>(smem, bid & 127, bid >> 7, abhi, ablo, ws, out);
}

extern "C" void kernel_launch(void* const* d_in, const int* in_sizes, int n_in,
                              void* d_out, int out_size, void* d_ws, size_t ws_size,
                              hipStream_t stream) {
    const float* x   = (const float*)d_in[0];
    const float* xsf = (const float*)d_in[1];
    const float* Wq  = (const float*)d_in[2];
    const float* bq  = (const float*)d_in[3];
    const float* Wk  = (const float*)d_in[4];
    const float* bk  = (const float*)d_in[5];
    const float* Wv  = (const float*)d_in[6];
    const float* bv  = (const float*)d_in[7];
    const float* Wp  = (const float*)d_in[8];
    const float* bp  = (const float*)d_in[9];
    float* ws  = (float*)d_ws;
    float* out = (float*)d_out;

    k_init<<<1, 256, 0, stream>>>(ws);
    k_mega<<<NBLK, 256, 0, stream>>>(x, xsf, Wq, bq, Wk, bk, Wv, bv, Wp, bp, ws, out);
}

// Round 11
// 191.396 us; speedup vs baseline: 4.8693x; 4.8693x over previous
//
#include <hip/hip_runtime.h>
#include <stdint.h>

// ---------------- workspace layout (float elements) ----------------
//  [0..3]  w absmax bits   [4..7] w_sf   [8..11] b_sf
//  [16..33] head absmax bits (q/k/v * 6 heads)
#define WS_WT     1024                        // w16 frag-order: 4 mats * 147456 ushort
#define WS_BI     (1024 + 4*147456)           // 590848 (float b_int)
#define WS_QBUF   (WS_BI + 1536)              // 592384: qkv fp32 (3*NE); later attn planes
#define NROW      8192
#define NE        (NROW*384)                  // 3145728
#define WS_C8     (WS_QBUF + 3*NE)            // xplanes (2*NE ushort) then q8/k8/vf
// total floats: WS_C8 + NE = 13,175,296 (~52.7 MB)

typedef __attribute__((ext_vector_type(4))) int      i32x4;
typedef __attribute__((ext_vector_type(4))) float    f32x4;
typedef __attribute__((ext_vector_type(8))) _Float16 f16x8;

// global -> LDS direct DMA, 16 B/lane; lds base wave-uniform, lane i -> base+i*16
__device__ __forceinline__ void gl2lds16(const void* g, void* lds_uniform) {
    __builtin_amdgcn_global_load_lds(
        (const __attribute__((address_space(1))) unsigned*)g,
        (__attribute__((address_space(3))) unsigned*)lds_uniform, 16, 0, 0);
}

__device__ __forceinline__ float blockmax_and_get(float lmax, float* red) {
    #pragma unroll
    for (int off = 32; off; off >>= 1) lmax = fmaxf(lmax, __shfl_xor(lmax, off, 64));
    int wv = threadIdx.x >> 6, ln = threadIdx.x & 63;
    if (ln == 0) red[wv] = lmax;
    __syncthreads();
    return fmaxf(fmaxf(red[0], red[1]), fmaxf(red[2], red[3]));
}

// fused: x -> f16 hi/lo planes (units 0..3071) + weight absmax (units 3072..3215)
__global__ __launch_bounds__(256) void k_xsplit_wmax(const float* __restrict__ src,
                                                     const float* __restrict__ xsf,
                                                     const float* __restrict__ w0,
                                                     const float* __restrict__ w1,
                                                     const float* __restrict__ w2,
                                                     const float* __restrict__ w3,
                                                     unsigned short* __restrict__ hip_,
                                                     unsigned short* __restrict__ lop_,
                                                     float* ws) {
    if (blockIdx.x >= 3072) {
        int u = blockIdx.x - 3072;
        int m = u / 36, chunk = u % 36;
        const float* w = (m == 0) ? w0 : (m == 1) ? w1 : (m == 2) ? w2 : w3;
        int base = chunk * 4096 + threadIdx.x;
        float lmax = 0.f;
        #pragma unroll
        for (int i = 0; i < 16; i++) lmax = fmaxf(lmax, fabsf(w[base + i * 256]));
        __shared__ float red[4];
        float m4 = blockmax_and_get(lmax, red);
        if (threadIdx.x == 0) atomicMax((unsigned int*)&ws[m], __float_as_uint(m4));
        return;
    }
    int gid = blockIdx.x * 256 + threadIdx.x;
    int e0 = gid * 4;
    int row = e0 / 384, k = e0 - row * 384;
    float xs = xsf[0];
    float4 v = *(const float4*)&src[e0];
    float f[4] = {v.x, v.y, v.z, v.w};
    unsigned short hb[4], lb[4];
    #pragma unroll
    for (int i = 0; i < 4; i++) {
        float xi = f[i] / xs;
        _Float16 h = (_Float16)xi;
        float hf = (float)h;
        _Float16 l = (_Float16)__fsub_rn(xi, hf);
        __builtin_memcpy(&hb[i], &h, 2);
        __builtin_memcpy(&lb[i], &l, 2);
    }
    int base = ((row >> 4) * 12 + (k >> 5)) * 512 + ((((k & 31) >> 3) << 4) + (row & 15)) * 8 + (k & 7);
    uint2 hp = make_uint2((unsigned)hb[0] | ((unsigned)hb[1] << 16),
                          (unsigned)hb[2] | ((unsigned)hb[3] << 16));
    uint2 lp = make_uint2((unsigned)lb[0] | ((unsigned)lb[1] << 16),
                          (unsigned)lb[2] | ((unsigned)lb[3] << 16));
    *(uint2*)(hip_ + base) = hp;
    *(uint2*)(lop_ + base) = lp;
}

// quantize weights -> f16 (exact, int8 range) in MFMA B-fragment order; biases fp32
__global__ __launch_bounds__(256) void k_wquant(const float* __restrict__ w0, const float* __restrict__ w1,
                                                const float* __restrict__ w2, const float* __restrict__ w3,
                                                const float* __restrict__ b0, const float* __restrict__ b1,
                                                const float* __restrict__ b2, const float* __restrict__ b3,
                                                const float* __restrict__ xsf, float* ws) {
    const unsigned* wu = (const unsigned*)ws;
    if (blockIdx.x < 576) {
        int m = blockIdx.x / 144, chunk = blockIdx.x % 144;
        const float* w = (m == 0) ? w0 : (m == 1) ? w1 : (m == 2) ? w2 : w3;
        float s = fmaxf(__uint_as_float(wu[m]), 1e-8f) / 127.0f;
        unsigned short* wt16 = (unsigned short*)(ws + WS_WT) + m * 147456;
        int base = chunk * 1024 + threadIdx.x;
        #pragma unroll
        for (int i = 0; i < 4; i++) {
            int e = base + i * 256;
            int o = e / 384, k = e - o * 384;
            float q = fminf(fmaxf(rintf(w[e] / s), -128.f), 127.f);
            _Float16 qh = (_Float16)q;
            unsigned short qb;
            __builtin_memcpy(&qb, &qh, 2);
            int idx = ((o >> 4) * 12 + (k >> 5)) * 512 + ((((k & 31) >> 3) << 4) + (o & 15)) * 8 + (k & 7);
            wt16[idx] = qb;
        }
    } else {
        for (int idx = threadIdx.x; idx < 1536; idx += 256) {
            int m = idx / 384, o = idx - m * 384;
            const float* b = (m == 0) ? b0 : (m == 1) ? b1 : (m == 2) ? b2 : b3;
            float s = fmaxf(__uint_as_float(wu[m]), 1e-8f) / 127.0f;
            float bsf = (m < 3) ? __fmul_rn(s, xsf[0]) : __fmul_rn(s, 0.00390625f);
            float bq = fminf(fmaxf(rintf(b[o] / bsf), -2147483648.0f), 2147483648.0f);
            ws[WS_BI + m * 384 + o] = bq;
            if (o == 0) { ws[4 + m] = s; ws[8 + m] = bsf; }
        }
    }
}

// LDS-staged MFMA GEMM with double-buffered staging (one barrier per K-iter).
// Block tile = (RTB*16) x 128; 4 waves: (w&1) row half, (w>>1) col half.
template<int RTB, bool QKV>
__global__ __launch_bounds__(256) void k_gemm_lds(const unsigned short* __restrict__ xhi,
                                                  const unsigned short* __restrict__ xlo,
                                                  const float* ws,
                                                  float* __restrict__ out_base,
                                                  float* ws_mut) {
    constexpr int NF = 2 * RTB + 8;          // fragments per buffer
    constexpr int RT = RTB / 2;              // rowtiles per wave
    __shared__ unsigned short smem[2][NF * 512];
    int mtile = blockIdx.x, nt = blockIdx.y;
    int mat = QKV ? (nt / 3) : 3;
    int cb  = QKV ? ((nt % 3) * 128) : (nt * 128);
    const unsigned short* w16 = (const unsigned short*)(ws + WS_WT) + mat * 147456;
    const float* bi = ws + WS_BI + mat * 384;
    float bsf = ws[8 + mat];
    float* out = QKV ? (out_base + mat * NE) : out_base;

    int tid = threadIdx.x, w = tid >> 6, lane = tid & 63;
    int rtg0 = mtile * RTB;
    int ctg0 = cb >> 4;
    int rl0 = (w & 1) * RT, cl0 = (w >> 1) * 4;

    auto stage = [&](int buf, int k) {
        #pragma unroll
        for (int i = 0; i < NF / 4; i++) {
            int f = w * (NF / 4) + i;
            const unsigned short* g;
            if (f < RTB)           g = xhi + ((rtg0 + f) * 12 + k) * 512;
            else if (f < 2 * RTB)  g = xlo + ((rtg0 + f - RTB) * 12 + k) * 512;
            else                   g = w16 + ((ctg0 + f - 2 * RTB) * 12 + k) * 512;
            gl2lds16(g + lane * 8, &smem[buf][f * 512]);
        }
    };

    f32x4 acc[RT][4] = {};
    stage(0, 0);
    __syncthreads();
    for (int k = 0; k < 12; k++) {
        if (k < 11) stage((k + 1) & 1, k + 1);   // prefetch overlaps compute
        const unsigned short* sb = smem[k & 1];
        f16x8 bf[4];
        #pragma unroll
        for (int ct = 0; ct < 4; ct++)
            bf[ct] = *(const f16x8*)&sb[(2 * RTB + cl0 + ct) * 512 + lane * 8];
        #pragma unroll
        for (int rt = 0; rt < RT; rt++) {
            f16x8 hi = *(const f16x8*)&sb[(rl0 + rt) * 512 + lane * 8];
            f16x8 lo = *(const f16x8*)&sb[(RTB + rl0 + rt) * 512 + lane * 8];
            #pragma unroll
            for (int ct = 0; ct < 4; ct++) {
                acc[rt][ct] = __builtin_amdgcn_mfma_f32_16x16x32_f16(lo, bf[ct], acc[rt][ct], 0, 0, 0);
                acc[rt][ct] = __builtin_amdgcn_mfma_f32_16x16x32_f16(hi, bf[ct], acc[rt][ct], 0, 0, 0);
            }
        }
        __syncthreads();   // drains prefetch vmcnt + guards buffer reuse
    }

    int quad = lane >> 4, l15 = lane & 15;
    float lmax = 0.f;
    #pragma unroll
    for (int rt = 0; rt < RT; rt++) {
        #pragma unroll
        for (int r = 0; r < 4; r++) {
            int row = (rtg0 + rl0 + rt) * 16 + quad * 4 + r;
            #pragma unroll
            for (int ct = 0; ct < 4; ct++) {
                int col = (ctg0 + cl0 + ct) * 16 + l15;
                float v = __fmul_rn(__fadd_rn(acc[rt][ct][r], bi[col]), bsf);
                lmax = fmaxf(lmax, fabsf(v));
                out[row * 384 + col] = v;
            }
        }
    }
    if (QKV) {
        #pragma unroll
        for (int off = 32; off; off >>= 1) lmax = fmaxf(lmax, __shfl_xor(lmax, off, 64));
        int hd = (cb >> 6) + (w >> 1);   // wave's 64 cols = one head
        if (lane == 0)
            atomicMax((unsigned int*)&ws_mut[16 + mat * 6 + hd], __float_as_uint(lmax));
    } else {
        if (mtile == 0 && nt == 0 && tid == 0) out[NE] = bsf;   // out_sf
    }
}

// per-head scale derivation (identical float ops across rounds)
struct HeadScales {
    float qsf, ksf, vsf, sf, x0i, bpoly, cint, expsf, s16, thirty;
};
__device__ __forceinline__ HeadScales head_scales(const float* ws, int h) {
    const unsigned* wu = (const unsigned*)ws;
    HeadScales r;
    r.qsf = fmaxf(__uint_as_float(wu[16 + h]), 1e-8f) / 127.0f;
    r.ksf = fmaxf(__uint_as_float(wu[22 + h]), 1e-8f) / 127.0f;
    r.vsf = fmaxf(__uint_as_float(wu[28 + h]), 1e-8f) / 127.0f;
    r.sf = __fmul_rn(r.ksf, r.qsf);
    const float X0f = -0.6931f;
    const float C0f = 0.35815147f;
    const float C1f = (float)(0.96963238 / 0.35815147);
    const float C2f = (float)(1.0 / 0.35815147);
    r.x0i   = floorf(X0f / r.sf);
    r.bpoly = floorf(C1f / r.sf);
    float sfsq = __fmul_rn(r.sf, r.sf);
    r.cint  = floorf(C2f / sfsq);
    float psf = __fmul_rn(C0f, sfsq);
    r.expsf = psf / 1073741824.0f;
    float rawmax = __fmul_rn(r.cint, 1073741824.0f);
    r.s16 = fmaxf(__fmul_rn(rawmax, r.expsf), 1e-8f) / 32767.0f;
    r.thirty = __fmul_rn(30.0f, r.x0i);
    return r;
}

__device__ __forceinline__ unsigned short f16bits(float x) {
    _Float16 h = (_Float16)x;
    unsigned short u;
    __builtin_memcpy(&u, &h, 2);
    return u;
}

// quantize q/k -> int8 row-major; v -> f16 in B-fragment-swizzled order
__global__ __launch_bounds__(256) void k_prequant(const float* __restrict__ qb,
                                                  const float* __restrict__ kb,
                                                  const float* __restrict__ vb,
                                                  const float* __restrict__ ws,
                                                  char* __restrict__ q8,
                                                  char* __restrict__ k8,
                                                  unsigned short* __restrict__ vf) {
    const unsigned* wu = (const unsigned*)ws;
    int sec = blockIdx.x / 3072;
    int id = (blockIdx.x % 3072) * 256 + threadIdx.x;
    if (sec < 2) {
        const float* src = sec ? kb : qb;
        int row = id / 96, c4 = (id % 96) * 4;
        int h = c4 >> 6;
        float s = fmaxf(__uint_as_float(wu[16 + (sec ? 6 : 0) + h]), 1e-8f) / 127.0f;
        float4 v = *(const float4*)&src[row * 384 + c4];
        int a0 = (int)fminf(fmaxf(rintf(v.x / s), -128.f), 127.f);
        int a1 = (int)fminf(fmaxf(rintf(v.y / s), -128.f), 127.f);
        int a2 = (int)fminf(fmaxf(rintf(v.z / s), -128.f), 127.f);
        int a3 = (int)fminf(fmaxf(rintf(v.w / s), -128.f), 127.f);
        unsigned pk = (unsigned)(a0 & 255) | ((unsigned)(a1 & 255) << 8) |
                      ((unsigned)(a2 & 255) << 16) | ((unsigned)(a3 & 255) << 24);
        ((unsigned*)(sec ? k8 : q8))[id] = pk;
    } else {
        int d = id & 63;
        int rest = id >> 6;
        int kvg = rest & 63;
        int bh = rest >> 6;
        int b = bh / 6, h = bh - (bh / 6) * 6;
        float s = fmaxf(__uint_as_float(wu[28 + h]), 1e-8f) / 127.0f;
        int kv0 = kvg * 4;
        unsigned pk01, pk23;
        {
            float v0 = vb[(b * 256 + kv0 + 0) * 384 + h * 64 + d];
            float v1 = vb[(b * 256 + kv0 + 1) * 384 + h * 64 + d];
            float v2 = vb[(b * 256 + kv0 + 2) * 384 + h * 64 + d];
            float v3 = vb[(b * 256 + kv0 + 3) * 384 + h * 64 + d];
            unsigned short u0 = f16bits(fminf(fmaxf(rintf(v0 / s), -128.f), 127.f));
            unsigned short u1 = f16bits(fminf(fmaxf(rintf(v1 / s), -128.f), 127.f));
            unsigned short u2 = f16bits(fminf(fmaxf(rintf(v2 / s), -128.f), 127.f));
            unsigned short u3 = f16bits(fminf(fmaxf(rintf(v3 / s), -128.f), 127.f));
            pk01 = (unsigned)u0 | ((unsigned)u1 << 16);
            pk23 = (unsigned)u2 | ((unsigned)u3 << 16);
        }
        int c = kv0 >> 5, quad = (kv0 >> 3) & 3, j0 = kv0 & 7;
        int base = ((bh * 8 + c) * 4 + (d >> 4)) * 512 + (quad * 16 + (d & 15)) * 8 + j0;
        uint2 pk = make_uint2(pk01, pk23);
        *(uint2*)&vf[base] = pk;
    }
}

// fused MFMA attention; epilogue writes hi/lo f16 planes (A-fragment order)
__global__ __launch_bounds__(256) void k_attn(const char* __restrict__ q8,
                                              const char* __restrict__ k8,
                                              const unsigned short* __restrict__ vf,
                                              const float* __restrict__ ws,
                                              unsigned short* __restrict__ abhi,
                                              unsigned short* __restrict__ ablo) {
    __shared__ _Float16 pS[4][64][8];
    int qt = blockIdx.x & 3, bh = blockIdx.x >> 2;
    int b = bh / 6, h = bh - (bh / 6) * 6;
    HeadScales S = head_scales(ws, h);
    float qsf = S.qsf, ksf = S.ksf, vsf = S.vsf;
    float sf = S.sf, x0i = S.x0i, bpoly = S.bpoly, cint = S.cint;
    float expsf = S.expsf, s16 = S.s16, thirty = S.thirty;

    int tid = threadIdx.x, w = tid >> 6, lane = tid & 63;
    int quad = lane >> 4, l15 = lane & 15;
    int strip0 = qt * 64 + w * 16;
    int ntiles = (strip0 >> 4) + 1;

    const i32x4 afrag = *(const i32x4*)(q8 + (b * 256 + strip0 + l15) * 384 + h * 64 + quad * 16);

    f32x4 xi[16];
    i32x4 zero4 = {0, 0, 0, 0};
    #pragma unroll
    for (int ct = 0; ct < 16; ct++) {
        if (ct < ntiles) {
            i32x4 bfrag = *(const i32x4*)(k8 + (b * 256 + ct * 16 + l15) * 384 + h * 64 + quad * 16);
            i32x4 c = __builtin_amdgcn_mfma_i32_16x16x64_i8(afrag, bfrag, zero4, 0, 0, 0);
            #pragma unroll
            for (int r = 0; r < 4; r++) {
                float wei = __fmul_rn(__fmul_rn(__fmul_rn((float)c[r], qsf), ksf), 0.125f);
                xi[ct][r] = wei / sf;
            }
        }
    }

    float NI = -__builtin_inff();
    f32x4 m = {NI, NI, NI, NI};
    #pragma unroll
    for (int ct = 0; ct < 16; ct++) {
        if (ct < ntiles) {
            bool last = (ct == ntiles - 1);
            #pragma unroll
            for (int r = 0; r < 4; r++)
                if (!last || (l15 <= quad * 4 + r)) m[r] = fmaxf(m[r], xi[ct][r]);
        }
    }
    #pragma unroll
    for (int o = 8; o; o >>= 1) {
        m.x = fmaxf(m.x, __shfl_xor(m.x, o));
        m.y = fmaxf(m.y, __shfl_xor(m.y, o));
        m.z = fmaxf(m.z, __shfl_xor(m.z, o));
        m.w = fmaxf(m.w, __shfl_xor(m.w, o));
    }

    f32x4 sum = {0.f, 0.f, 0.f, 0.f};
    #pragma unroll
    for (int ct = 0; ct < 16; ct++) {
        if (ct < ntiles) {
            bool last = (ct == ntiles - 1);
            #pragma unroll
            for (int r = 0; r < 4; r++) {
                float ei = 0.f;
                if (!last || (l15 <= quad * 4 + r)) {
                    float xsv = fmaxf(__fsub_rn(xi[ct][r], m[r]), thirty);
                    float qf = floorf(xsv / x0i);
                    float rr = __fsub_rn(xsv, __fmul_rn(x0i, qf));
                    float z = __fadd_rn(__fmul_rn(__fadd_rn(rr, bpoly), rr), cint);
                    float p2 = ldexpf(1.0f, 30 - (int)qf);
                    float eraw = fmaxf(floorf(__fmul_rn(z, p2)), 0.0f);
                    float esc = __fmul_rn(eraw, expsf);
                    float q16 = fminf(fmaxf(rintf(esc / s16), -32768.f), 32767.f);
                    float e = __fmul_rn(q16, s16);
                    ei = e / s16;
                }
                xi[ct][r] = ei;
                sum[r] += ei;
            }
        }
    }
    #pragma unroll
    for (int o = 8; o; o >>= 1) {
        sum.x += __shfl_xor(sum.x, o);
        sum.y += __shfl_xor(sum.y, o);
        sum.z += __shfl_xor(sum.z, o);
        sum.w += __shfl_xor(sum.w, o);
    }
    f32x4 fac;
    #pragma unroll
    for (int r = 0; r < 4; r++) fac[r] = floorf(4294967296.0f / sum[r]);

    #pragma unroll
    for (int ct = 0; ct < 16; ct++) {
        #pragma unroll
        for (int r = 0; r < 4; r++) {
            if (ct < ntiles)
                xi[ct][r] = floorf(__fmul_rn(__fmul_rn(xi[ct][r], fac[r]), 5.9604644775390625e-08f));
            else
                xi[ct][r] = 0.f;
        }
    }

    f32x4 o[4] = {};
    int nch = (ntiles + 1) >> 1;
    #pragma unroll
    for (int c = 0; c < 8; c++) {
        if (c < nch) {
            #pragma unroll
            for (int t2 = 0; t2 < 2; t2++) {
                int qd = t2 * 2 + (l15 >> 3);
                #pragma unroll
                for (int r = 0; r < 4; r++)
                    pS[w][qd * 16 + quad * 4 + r][l15 & 7] = (_Float16)xi[2 * c + t2][r];
            }
            f16x8 pa = *(f16x8*)&pS[w][lane][0];
            int vbase = ((bh * 8 + c) * 4) * 512 + lane * 8;
            #pragma unroll
            for (int cc = 0; cc < 4; cc++) {
                f16x8 vbf = *(const f16x8*)&vf[vbase + cc * 512];
                o[cc] = __builtin_amdgcn_mfma_f32_16x16x32_f16(pa, vbf, o[cc], 0, 0, 0);
            }
        }
    }

    // epilogue: out = ipv*vsf/256, split to f16 hi/lo planes in A-frag order
    int rowt12 = ((b * 256 + strip0) >> 4) * 12;
    #pragma unroll
    for (int cc = 0; cc < 4; cc++) {
        int fb = (rowt12 + h * 2 + (cc >> 1)) * 512;
        int sub = ((cc & 1) * 2 + (l15 >> 3)) * 16;
        #pragma unroll
        for (int r = 0; r < 4; r++) {
            float v = __fmul_rn(__fmul_rn(o[cc][r], vsf), 0.00390625f);
            _Float16 hh = (_Float16)v;
            float hf = (float)hh;
            _Float16 ll = (_Float16)__fsub_rn(v, hf);
            unsigned short hbb, lbb;
            __builtin_memcpy(&hbb, &hh, 2);
            __builtin_memcpy(&lbb, &ll, 2);
            int idx = fb + (sub + quad * 4 + r) * 8 + (l15 & 7);
            abhi[idx] = hbb;
            ablo[idx] = lbb;
        }
    }
}

extern "C" void kernel_launch(void* const* d_in, const int* in_sizes, int n_in,
                              void* d_out, int out_size, void* d_ws, size_t ws_size,
                              hipStream_t stream) {
    const float* x   = (const float*)d_in[0];
    const float* xsf = (const float*)d_in[1];
    const float* Wq  = (const float*)d_in[2];
    const float* bq  = (const float*)d_in[3];
    const float* Wk  = (const float*)d_in[4];
    const float* bk  = (const float*)d_in[5];
    const float* Wv  = (const float*)d_in[6];
    const float* bv  = (const float*)d_in[7];
    const float* Wp  = (const float*)d_in[8];
    const float* bp  = (const float*)d_in[9];
    float* ws  = (float*)d_ws;
    float* out = (float*)d_out;
    float* qkv = ws + WS_QBUF;

    unsigned short* xhi = (unsigned short*)(ws + WS_C8);
    unsigned short* xlo = xhi + NE;
    char*  q8  = (char*)(ws + WS_C8);
    char*  k8  = q8 + NE;
    unsigned short* vfp = (unsigned short*)(k8 + NE);
    unsigned short* abhi = (unsigned short*)(ws + WS_QBUF + NE);  // dead k-region
    unsigned short* ablo = abhi + NE;

    hipMemsetAsync(d_ws, 0, 1024, stream);   // zero scalar/atomic slots (capture-legal)
    k_xsplit_wmax<<<3216, 256, 0, stream>>>(x, xsf, Wq, Wk, Wv, Wp, xhi, xlo, ws);
    k_wquant<<<577, 256, 0, stream>>>(Wq, Wk, Wv, Wp, bq, bk, bv, bp, xsf, ws);
    k_gemm_lds<8, true><<<dim3(64, 9), 256, 0, stream>>>(xhi, xlo, ws, qkv, ws);
    k_prequant<<<9216, 256, 0, stream>>>(qkv, qkv + NE, qkv + 2 * NE, ws, q8, k8, vfp);
    k_attn<<<768, 256, 0, stream>>>(q8, k8, vfp, ws, abhi, ablo);
    k_gemm_lds<4, false><<<dim3(128, 3), 256, 0, stream>>>(abhi, ablo, ws, out, ws);
}

// Round 12
// 190.507 us; speedup vs baseline: 4.8920x; 1.0047x over previous
//
#include <hip/hip_runtime.h>
#include <stdint.h>

// ---------------- workspace layout (float elements) ----------------
//  [0..3]  w absmax bits   [4..7] w_sf   [8..11] b_sf
//  [16..33] head absmax bits (q/k/v * 6 heads)
#define WS_WT     1024                        // w16 frag-order: 4 mats * 147456 ushort
#define WS_BI     (1024 + 4*147456)           // 590848 (float b_int)
#define WS_QBUF   (WS_BI + 1536)              // 592384: qkv fp32 (3*NE); later attn planes
#define NROW      8192
#define NE        (NROW*384)                  // 3145728
#define WS_C8     (WS_QBUF + 3*NE)            // xplanes (2*NE ushort) then q8/k8/vf
// total floats: WS_C8 + NE = 13,175,296 (~52.7 MB)

typedef __attribute__((ext_vector_type(4))) int      i32x4;
typedef __attribute__((ext_vector_type(4))) float    f32x4;
typedef __attribute__((ext_vector_type(8))) _Float16 f16x8;

__device__ __forceinline__ float blockmax_and_get(float lmax, float* red) {
    #pragma unroll
    for (int off = 32; off; off >>= 1) lmax = fmaxf(lmax, __shfl_xor(lmax, off, 64));
    int wv = threadIdx.x >> 6, ln = threadIdx.x & 63;
    if (ln == 0) red[wv] = lmax;
    __syncthreads();
    return fmaxf(fmaxf(red[0], red[1]), fmaxf(red[2], red[3]));
}

// fused: x -> f16 hi/lo planes (units 0..3071) + weight absmax (units 3072..3215)
__global__ __launch_bounds__(256) void k_xsplit_wmax(const float* __restrict__ src,
                                                     const float* __restrict__ xsf,
                                                     const float* __restrict__ w0,
                                                     const float* __restrict__ w1,
                                                     const float* __restrict__ w2,
                                                     const float* __restrict__ w3,
                                                     unsigned short* __restrict__ hip_,
                                                     unsigned short* __restrict__ lop_,
                                                     float* ws) {
    if (blockIdx.x >= 3072) {
        int u = blockIdx.x - 3072;
        int m = u / 36, chunk = u % 36;
        const float* w = (m == 0) ? w0 : (m == 1) ? w1 : (m == 2) ? w2 : w3;
        int base = chunk * 4096 + threadIdx.x;
        float lmax = 0.f;
        #pragma unroll
        for (int i = 0; i < 16; i++) lmax = fmaxf(lmax, fabsf(w[base + i * 256]));
        __shared__ float red[4];
        float m4 = blockmax_and_get(lmax, red);
        if (threadIdx.x == 0) atomicMax((unsigned int*)&ws[m], __float_as_uint(m4));
        return;
    }
    int gid = blockIdx.x * 256 + threadIdx.x;
    int e0 = gid * 4;
    int row = e0 / 384, k = e0 - row * 384;
    float xs = xsf[0];
    float4 v = *(const float4*)&src[e0];
    float f[4] = {v.x, v.y, v.z, v.w};
    unsigned short hb[4], lb[4];
    #pragma unroll
    for (int i = 0; i < 4; i++) {
        float xi = f[i] / xs;
        _Float16 h = (_Float16)xi;
        float hf = (float)h;
        _Float16 l = (_Float16)__fsub_rn(xi, hf);
        __builtin_memcpy(&hb[i], &h, 2);
        __builtin_memcpy(&lb[i], &l, 2);
    }
    int base = ((row >> 4) * 12 + (k >> 5)) * 512 + ((((k & 31) >> 3) << 4) + (row & 15)) * 8 + (k & 7);
    uint2 hp = make_uint2((unsigned)hb[0] | ((unsigned)hb[1] << 16),
                          (unsigned)hb[2] | ((unsigned)hb[3] << 16));
    uint2 lp = make_uint2((unsigned)lb[0] | ((unsigned)lb[1] << 16),
                          (unsigned)lb[2] | ((unsigned)lb[3] << 16));
    *(uint2*)(hip_ + base) = hp;
    *(uint2*)(lop_ + base) = lp;
}

// quantize weights -> f16 (exact, int8 range) in MFMA B-fragment order; biases fp32
__global__ __launch_bounds__(256) void k_wquant(const float* __restrict__ w0, const float* __restrict__ w1,
                                                const float* __restrict__ w2, const float* __restrict__ w3,
                                                const float* __restrict__ b0, const float* __restrict__ b1,
                                                const float* __restrict__ b2, const float* __restrict__ b3,
                                                const float* __restrict__ xsf, float* ws) {
    const unsigned* wu = (const unsigned*)ws;
    if (blockIdx.x < 576) {
        int m = blockIdx.x / 144, chunk = blockIdx.x % 144;
        const float* w = (m == 0) ? w0 : (m == 1) ? w1 : (m == 2) ? w2 : w3;
        float s = fmaxf(__uint_as_float(wu[m]), 1e-8f) / 127.0f;
        unsigned short* wt16 = (unsigned short*)(ws + WS_WT) + m * 147456;
        int base = chunk * 1024 + threadIdx.x;
        #pragma unroll
        for (int i = 0; i < 4; i++) {
            int e = base + i * 256;
            int o = e / 384, k = e - o * 384;
            float q = fminf(fmaxf(rintf(w[e] / s), -128.f), 127.f);
            _Float16 qh = (_Float16)q;
            unsigned short qb;
            __builtin_memcpy(&qb, &qh, 2);
            int idx = ((o >> 4) * 12 + (k >> 5)) * 512 + ((((k & 31) >> 3) << 4) + (o & 15)) * 8 + (k & 7);
            wt16[idx] = qb;
        }
    } else {
        for (int idx = threadIdx.x; idx < 1536; idx += 256) {
            int m = idx / 384, o = idx - m * 384;
            const float* b = (m == 0) ? b0 : (m == 1) ? b1 : (m == 2) ? b2 : b3;
            float s = fmaxf(__uint_as_float(wu[m]), 1e-8f) / 127.0f;
            float bsf = (m < 3) ? __fmul_rn(s, xsf[0]) : __fmul_rn(s, 0.00390625f);
            float bq = fminf(fmaxf(rintf(b[o] / bsf), -2147483648.0f), 2147483648.0f);
            ws[WS_BI + m * 384 + o] = bq;
            if (o == 0) { ws[4 + m] = s; ws[8 + m] = bsf; }
        }
    }
}

// MFMA GEMM, VGPR-staged pipeline: ordinary global_load_dwordx4 prefetch
// (pipelined VMEM queue) -> compute current chunk from LDS -> ds_write next
// chunk -> barrier. No registers live across barriers (g0..g5 are named
// scalars; no arrays => SROA guaranteed, no scratch).
// Block tile = (RTB*16) x 128; 4 waves: (w&1) row half, (w>>1) col half.
// Frag id f = w*PW+i; [0..RTB)=A-hi, [RTB..2RTB)=A-lo, [2RTB..2RTB+8)=B.
#define FRAG_PTR(F, KK)                                                          \
    ((F) < RTB ? xhi + (((rtg0 + (F)) * 12 + (KK)) * 512) + lane * 8             \
     : (F) < 2 * RTB ? xlo + (((rtg0 + (F) - RTB) * 12 + (KK)) * 512) + lane * 8 \
     : w16 + (((ctg0 + (F) - 2 * RTB) * 12 + (KK)) * 512) + lane * 8)

template<int RTB, bool QKV>
__global__ __launch_bounds__(256) void k_gemm_p(const unsigned short* __restrict__ xhi,
                                                const unsigned short* __restrict__ xlo,
                                                const float* ws,
                                                float* __restrict__ out_base,
                                                float* ws_mut) {
    constexpr int NF = 2 * RTB + 8;          // fragments per chunk
    constexpr int PW = NF / 4;               // fragments staged per wave (6 or 4)
    constexpr int RT = RTB / 2;              // rowtiles per wave
    __shared__ unsigned short smem[2][NF * 512];
    int mtile = blockIdx.x, nt = blockIdx.y;
    int mat = QKV ? (nt / 3) : 3;
    int cb  = QKV ? ((nt % 3) * 128) : (nt * 128);
    const unsigned short* w16 = (const unsigned short*)(ws + WS_WT) + mat * 147456;
    const float* bi = ws + WS_BI + mat * 384;
    float bsf = ws[8 + mat];
    float* out = QKV ? (out_base + mat * NE) : out_base;

    int tid = threadIdx.x, w = tid >> 6, lane = tid & 63;
    int rtg0 = mtile * RTB;
    int ctg0 = cb >> 4;
    int rl0 = (w & 1) * RT, cl0 = (w >> 1) * 4;
    int f0 = w * PW;

    // prologue: chunk 0 -> regs -> buf0 -> barrier
    uint4 g0, g1, g2, g3, g4, g5;
    g0 = *(const uint4*)FRAG_PTR(f0 + 0, 0);
    g1 = *(const uint4*)FRAG_PTR(f0 + 1, 0);
    g2 = *(const uint4*)FRAG_PTR(f0 + 2, 0);
    g3 = *(const uint4*)FRAG_PTR(f0 + 3, 0);
    if (PW > 4) {
        g4 = *(const uint4*)FRAG_PTR(f0 + 4, 0);
        g5 = *(const uint4*)FRAG_PTR(f0 + 5, 0);
    }
    *(uint4*)&smem[0][(f0 + 0) * 512 + lane * 8] = g0;
    *(uint4*)&smem[0][(f0 + 1) * 512 + lane * 8] = g1;
    *(uint4*)&smem[0][(f0 + 2) * 512 + lane * 8] = g2;
    *(uint4*)&smem[0][(f0 + 3) * 512 + lane * 8] = g3;
    if (PW > 4) {
        *(uint4*)&smem[0][(f0 + 4) * 512 + lane * 8] = g4;
        *(uint4*)&smem[0][(f0 + 5) * 512 + lane * 8] = g5;
    }
    __syncthreads();

    f32x4 acc[RT][4] = {};
    for (int k = 0; k < 12; k++) {
        const int buf = k & 1;
        // 1) prefetch chunk k+1 into regs (pipelined VMEM, overlaps compute)
        if (k < 11) {
            g0 = *(const uint4*)FRAG_PTR(f0 + 0, k + 1);
            g1 = *(const uint4*)FRAG_PTR(f0 + 1, k + 1);
            g2 = *(const uint4*)FRAG_PTR(f0 + 2, k + 1);
            g3 = *(const uint4*)FRAG_PTR(f0 + 3, k + 1);
            if (PW > 4) {
                g4 = *(const uint4*)FRAG_PTR(f0 + 4, k + 1);
                g5 = *(const uint4*)FRAG_PTR(f0 + 5, k + 1);
            }
        }
        // 2) compute chunk k from LDS
        f16x8 bf[4];
        #pragma unroll
        for (int ct = 0; ct < 4; ct++)
            bf[ct] = *(const f16x8*)&smem[buf][(2 * RTB + cl0 + ct) * 512 + lane * 8];
        #pragma unroll
        for (int rt = 0; rt < RT; rt++) {
            f16x8 hi = *(const f16x8*)&smem[buf][(rl0 + rt) * 512 + lane * 8];
            f16x8 lo = *(const f16x8*)&smem[buf][(RTB + rl0 + rt) * 512 + lane * 8];
            #pragma unroll
            for (int ct = 0; ct < 4; ct++) {
                acc[rt][ct] = __builtin_amdgcn_mfma_f32_16x16x32_f16(lo, bf[ct], acc[rt][ct], 0, 0, 0);
                acc[rt][ct] = __builtin_amdgcn_mfma_f32_16x16x32_f16(hi, bf[ct], acc[rt][ct], 0, 0, 0);
            }
        }
        // 3) deposit chunk k+1 into other buffer (consumes vmcnt), 4) barrier
        if (k < 11) {
            const int nbuf = buf ^ 1;
            *(uint4*)&smem[nbuf][(f0 + 0) * 512 + lane * 8] = g0;
            *(uint4*)&smem[nbuf][(f0 + 1) * 512 + lane * 8] = g1;
            *(uint4*)&smem[nbuf][(f0 + 2) * 512 + lane * 8] = g2;
            *(uint4*)&smem[nbuf][(f0 + 3) * 512 + lane * 8] = g3;
            if (PW > 4) {
                *(uint4*)&smem[nbuf][(f0 + 4) * 512 + lane * 8] = g4;
                *(uint4*)&smem[nbuf][(f0 + 5) * 512 + lane * 8] = g5;
            }
        }
        __syncthreads();
    }

    int quad = lane >> 4, l15 = lane & 15;
    float lmax = 0.f;
    #pragma unroll
    for (int rt = 0; rt < RT; rt++) {
        #pragma unroll
        for (int r = 0; r < 4; r++) {
            int row = (rtg0 + rl0 + rt) * 16 + quad * 4 + r;
            #pragma unroll
            for (int ct = 0; ct < 4; ct++) {
                int col = (ctg0 + cl0 + ct) * 16 + l15;
                float v = __fmul_rn(__fadd_rn(acc[rt][ct][r], bi[col]), bsf);
                lmax = fmaxf(lmax, fabsf(v));
                out[row * 384 + col] = v;
            }
        }
    }
    if (QKV) {
        #pragma unroll
        for (int off = 32; off; off >>= 1) lmax = fmaxf(lmax, __shfl_xor(lmax, off, 64));
        int hd = (cb >> 6) + (w >> 1);   // wave's 64 cols = one head
        if (lane == 0)
            atomicMax((unsigned int*)&ws_mut[16 + mat * 6 + hd], __float_as_uint(lmax));
    } else {
        if (mtile == 0 && nt == 0 && tid == 0) out[NE] = bsf;   // out_sf
    }
}

// per-head scale derivation (identical float ops across rounds)
struct HeadScales {
    float qsf, ksf, vsf, sf, x0i, bpoly, cint, expsf, s16, thirty;
};
__device__ __forceinline__ HeadScales head_scales(const float* ws, int h) {
    const unsigned* wu = (const unsigned*)ws;
    HeadScales r;
    r.qsf = fmaxf(__uint_as_float(wu[16 + h]), 1e-8f) / 127.0f;
    r.ksf = fmaxf(__uint_as_float(wu[22 + h]), 1e-8f) / 127.0f;
    r.vsf = fmaxf(__uint_as_float(wu[28 + h]), 1e-8f) / 127.0f;
    r.sf = __fmul_rn(r.ksf, r.qsf);
    const float X0f = -0.6931f;
    const float C0f = 0.35815147f;
    const float C1f = (float)(0.96963238 / 0.35815147);
    const float C2f = (float)(1.0 / 0.35815147);
    r.x0i   = floorf(X0f / r.sf);
    r.bpoly = floorf(C1f / r.sf);
    float sfsq = __fmul_rn(r.sf, r.sf);
    r.cint  = floorf(C2f / sfsq);
    float psf = __fmul_rn(C0f, sfsq);
    r.expsf = psf / 1073741824.0f;
    float rawmax = __fmul_rn(r.cint, 1073741824.0f);
    r.s16 = fmaxf(__fmul_rn(rawmax, r.expsf), 1e-8f) / 32767.0f;
    r.thirty = __fmul_rn(30.0f, r.x0i);
    return r;
}

__device__ __forceinline__ unsigned short f16bits(float x) {
    _Float16 h = (_Float16)x;
    unsigned short u;
    __builtin_memcpy(&u, &h, 2);
    return u;
}

// quantize q/k -> int8 row-major; v -> f16 in B-fragment-swizzled order
__global__ __launch_bounds__(256) void k_prequant(const float* __restrict__ qb,
                                                  const float* __restrict__ kb,
                                                  const float* __restrict__ vb,
                                                  const float* __restrict__ ws,
                                                  char* __restrict__ q8,
                                                  char* __restrict__ k8,
                                                  unsigned short* __restrict__ vf) {
    const unsigned* wu = (const unsigned*)ws;
    int sec = blockIdx.x / 3072;
    int id = (blockIdx.x % 3072) * 256 + threadIdx.x;
    if (sec < 2) {
        const float* src = sec ? kb : qb;
        int row = id / 96, c4 = (id % 96) * 4;
        int h = c4 >> 6;
        float s = fmaxf(__uint_as_float(wu[16 + (sec ? 6 : 0) + h]), 1e-8f) / 127.0f;
        float4 v = *(const float4*)&src[row * 384 + c4];
        int a0 = (int)fminf(fmaxf(rintf(v.x / s), -128.f), 127.f);
        int a1 = (int)fminf(fmaxf(rintf(v.y / s), -128.f), 127.f);
        int a2 = (int)fminf(fmaxf(rintf(v.z / s), -128.f), 127.f);
        int a3 = (int)fminf(fmaxf(rintf(v.w / s), -128.f), 127.f);
        unsigned pk = (unsigned)(a0 & 255) | ((unsigned)(a1 & 255) << 8) |
                      ((unsigned)(a2 & 255) << 16) | ((unsigned)(a3 & 255) << 24);
        ((unsigned*)(sec ? k8 : q8))[id] = pk;
    } else {
        int d = id & 63;
        int rest = id >> 6;
        int kvg = rest & 63;
        int bh = rest >> 6;
        int b = bh / 6, h = bh - (bh / 6) * 6;
        float s = fmaxf(__uint_as_float(wu[28 + h]), 1e-8f) / 127.0f;
        int kv0 = kvg * 4;
        unsigned pk01, pk23;
        {
            float v0 = vb[(b * 256 + kv0 + 0) * 384 + h * 64 + d];
            float v1 = vb[(b * 256 + kv0 + 1) * 384 + h * 64 + d];
            float v2 = vb[(b * 256 + kv0 + 2) * 384 + h * 64 + d];
            float v3 = vb[(b * 256 + kv0 + 3) * 384 + h * 64 + d];
            unsigned short u0 = f16bits(fminf(fmaxf(rintf(v0 / s), -128.f), 127.f));
            unsigned short u1 = f16bits(fminf(fmaxf(rintf(v1 / s), -128.f), 127.f));
            unsigned short u2 = f16bits(fminf(fmaxf(rintf(v2 / s), -128.f), 127.f));
            unsigned short u3 = f16bits(fminf(fmaxf(rintf(v3 / s), -128.f), 127.f));
            pk01 = (unsigned)u0 | ((unsigned)u1 << 16);
            pk23 = (unsigned)u2 | ((unsigned)u3 << 16);
        }
        int c = kv0 >> 5, quad = (kv0 >> 3) & 3, j0 = kv0 & 7;
        int base = ((bh * 8 + c) * 4 + (d >> 4)) * 512 + (quad * 16 + (d & 15)) * 8 + j0;
        uint2 pk = make_uint2(pk01, pk23);
        *(uint2*)&vf[base] = pk;
    }
}

// fused MFMA attention; epilogue writes hi/lo f16 planes (A-fragment order)
__global__ __launch_bounds__(256) void k_attn(const char* __restrict__ q8,
                                              const char* __restrict__ k8,
                                              const unsigned short* __restrict__ vf,
                                              const float* __restrict__ ws,
                                              unsigned short* __restrict__ abhi,
                                              unsigned short* __restrict__ ablo) {
    __shared__ _Float16 pS[4][64][8];
    int qt = blockIdx.x & 3, bh = blockIdx.x >> 2;
    int b = bh / 6, h = bh - (bh / 6) * 6;
    HeadScales S = head_scales(ws, h);
    float qsf = S.qsf, ksf = S.ksf, vsf = S.vsf;
    float sf = S.sf, x0i = S.x0i, bpoly = S.bpoly, cint = S.cint;
    float expsf = S.expsf, s16 = S.s16, thirty = S.thirty;

    int tid = threadIdx.x, w = tid >> 6, lane = tid & 63;
    int quad = lane >> 4, l15 = lane & 15;
    int strip0 = qt * 64 + w * 16;
    int ntiles = (strip0 >> 4) + 1;

    const i32x4 afrag = *(const i32x4*)(q8 + (b * 256 + strip0 + l15) * 384 + h * 64 + quad * 16);

    f32x4 xi[16];
    i32x4 zero4 = {0, 0, 0, 0};
    #pragma unroll
    for (int ct = 0; ct < 16; ct++) {
        if (ct < ntiles) {
            i32x4 bfrag = *(const i32x4*)(k8 + (b * 256 + ct * 16 + l15) * 384 + h * 64 + quad * 16);
            i32x4 c = __builtin_amdgcn_mfma_i32_16x16x64_i8(afrag, bfrag, zero4, 0, 0, 0);
            #pragma unroll
            for (int r = 0; r < 4; r++) {
                float wei = __fmul_rn(__fmul_rn(__fmul_rn((float)c[r], qsf), ksf), 0.125f);
                xi[ct][r] = wei / sf;
            }
        }
    }

    float NI = -__builtin_inff();
    f32x4 m = {NI, NI, NI, NI};
    #pragma unroll
    for (int ct = 0; ct < 16; ct++) {
        if (ct < ntiles) {
            bool last = (ct == ntiles - 1);
            #pragma unroll
            for (int r = 0; r < 4; r++)
                if (!last || (l15 <= quad * 4 + r)) m[r] = fmaxf(m[r], xi[ct][r]);
        }
    }
    #pragma unroll
    for (int o = 8; o; o >>= 1) {
        m.x = fmaxf(m.x, __shfl_xor(m.x, o));
        m.y = fmaxf(m.y, __shfl_xor(m.y, o));
        m.z = fmaxf(m.z, __shfl_xor(m.z, o));
        m.w = fmaxf(m.w, __shfl_xor(m.w, o));
    }

    f32x4 sum = {0.f, 0.f, 0.f, 0.f};
    #pragma unroll
    for (int ct = 0; ct < 16; ct++) {
        if (ct < ntiles) {
            bool last = (ct == ntiles - 1);
            #pragma unroll
            for (int r = 0; r < 4; r++) {
                float ei = 0.f;
                if (!last || (l15 <= quad * 4 + r)) {
                    float xsv = fmaxf(__fsub_rn(xi[ct][r], m[r]), thirty);
                    float qf = floorf(xsv / x0i);
                    float rr = __fsub_rn(xsv, __fmul_rn(x0i, qf));
                    float z = __fadd_rn(__fmul_rn(__fadd_rn(rr, bpoly), rr), cint);
                    float p2 = ldexpf(1.0f, 30 - (int)qf);
                    float eraw = fmaxf(floorf(__fmul_rn(z, p2)), 0.0f);
                    float esc = __fmul_rn(eraw, expsf);
                    float q16 = fminf(fmaxf(rintf(esc / s16), -32768.f), 32767.f);
                    float e = __fmul_rn(q16, s16);
                    ei = e / s16;
                }
                xi[ct][r] = ei;
                sum[r] += ei;
            }
        }
    }
    #pragma unroll
    for (int o = 8; o; o >>= 1) {
        sum.x += __shfl_xor(sum.x, o);
        sum.y += __shfl_xor(sum.y, o);
        sum.z += __shfl_xor(sum.z, o);
        sum.w += __shfl_xor(sum.w, o);
    }
    f32x4 fac;
    #pragma unroll
    for (int r = 0; r < 4; r++) fac[r] = floorf(4294967296.0f / sum[r]);

    #pragma unroll
    for (int ct = 0; ct < 16; ct++) {
        #pragma unroll
        for (int r = 0; r < 4; r++) {
            if (ct < ntiles)
                xi[ct][r] = floorf(__fmul_rn(__fmul_rn(xi[ct][r], fac[r]), 5.9604644775390625e-08f));
            else
                xi[ct][r] = 0.f;
        }
    }

    f32x4 o[4] = {};
    int nch = (ntiles + 1) >> 1;
    #pragma unroll
    for (int c = 0; c < 8; c++) {
        if (c < nch) {
            #pragma unroll
            for (int t2 = 0; t2 < 2; t2++) {
                int qd = t2 * 2 + (l15 >> 3);
                #pragma unroll
                for (int r = 0; r < 4; r++)
                    pS[w][qd * 16 + quad * 4 + r][l15 & 7] = (_Float16)xi[2 * c + t2][r];
            }
            f16x8 pa = *(f16x8*)&pS[w][lane][0];
            int vbase = ((bh * 8 + c) * 4) * 512 + lane * 8;
            #pragma unroll
            for (int cc = 0; cc < 4; cc++) {
                f16x8 vbf = *(const f16x8*)&vf[vbase + cc * 512];
                o[cc] = __builtin_amdgcn_mfma_f32_16x16x32_f16(pa, vbf, o[cc], 0, 0, 0);
            }
        }
    }

    // epilogue: out = ipv*vsf/256, split to f16 hi/lo planes in A-frag order
    int rowt12 = ((b * 256 + strip0) >> 4) * 12;
    #pragma unroll
    for (int cc = 0; cc < 4; cc++) {
        int fb = (rowt12 + h * 2 + (cc >> 1)) * 512;
        int sub = ((cc & 1) * 2 + (l15 >> 3)) * 16;
        #pragma unroll
        for (int r = 0; r < 4; r++) {
            float v = __fmul_rn(__fmul_rn(o[cc][r], vsf), 0.00390625f);
            _Float16 hh = (_Float16)v;
            float hf = (float)hh;
            _Float16 ll = (_Float16)__fsub_rn(v, hf);
            unsigned short hbb, lbb;
            __builtin_memcpy(&hbb, &hh, 2);
            __builtin_memcpy(&lbb, &ll, 2);
            int idx = fb + (sub + quad * 4 + r) * 8 + (l15 & 7);
            abhi[idx] = hbb;
            ablo[idx] = lbb;
        }
    }
}

extern "C" void kernel_launch(void* const* d_in, const int* in_sizes, int n_in,
                              void* d_out, int out_size, void* d_ws, size_t ws_size,
                              hipStream_t stream) {
    const float* x   = (const float*)d_in[0];
    const float* xsf = (const float*)d_in[1];
    const float* Wq  = (const float*)d_in[2];
    const float* bq  = (const float*)d_in[3];
    const float* Wk  = (const float*)d_in[4];
    const float* bk  = (const float*)d_in[5];
    const float* Wv  = (const float*)d_in[6];
    const float* bv  = (const float*)d_in[7];
    const float* Wp  = (const float*)d_in[8];
    const float* bp  = (const float*)d_in[9];
    float* ws  = (float*)d_ws;
    float* out = (float*)d_out;
    float* qkv = ws + WS_QBUF;

    unsigned short* xhi = (unsigned short*)(ws + WS_C8);
    unsigned short* xlo = xhi + NE;
    char*  q8  = (char*)(ws + WS_C8);
    char*  k8  = q8 + NE;
    unsigned short* vfp = (unsigned short*)(k8 + NE);
    unsigned short* abhi = (unsigned short*)(ws + WS_QBUF + NE);  // dead k-region
    unsigned short* ablo = abhi + NE;

    hipMemsetAsync(d_ws, 0, 1024, stream);   // zero scalar/atomic slots (capture-legal)
    k_xsplit_wmax<<<3216, 256, 0, stream>>>(x, xsf, Wq, Wk, Wv, Wp, xhi, xlo, ws);
    k_wquant<<<577, 256, 0, stream>>>(Wq, Wk, Wv, Wp, bq, bk, bv, bp, xsf, ws);
    k_gemm_p<8, true><<<dim3(64, 9), 256, 0, stream>>>(xhi, xlo, ws, qkv, ws);
    k_prequant<<<9216, 256, 0, stream>>>(qkv, qkv + NE, qkv + 2 * NE, ws, q8, k8, vfp);
    k_attn<<<768, 256, 0, stream>>>(q8, k8, vfp, ws, abhi, ablo);
    k_gemm_p<4, false><<<dim3(128, 3), 256, 0, stream>>>(abhi, ablo, ws, out, ws);
}